// Round 1
// baseline (568.066 us; speedup 1.0000x reference)
//
#include <hip/hip_runtime.h>

typedef __bf16 bf16x8 __attribute__((ext_vector_type(8)));
typedef float  f32x4  __attribute__((ext_vector_type(4)));

__device__ __forceinline__ unsigned short f2bf(float x){
  unsigned int u = __float_as_uint(x);
  u += 0x7fffu + ((u >> 16) & 1u);          // RNE
  return (unsigned short)(u >> 16);
}
__device__ __forceinline__ float bf2f(unsigned short h){
  return __uint_as_float(((unsigned int)h) << 16);
}
__device__ __forceinline__ float sigm(float x){
  // 1/(1+2^(-x*log2e)) ; saturates correctly at +-inf
  return __builtin_amdgcn_rcpf(1.0f + __builtin_amdgcn_exp2f(-1.44269504f * x));
}
__device__ __forceinline__ float tanh_(float x){
  // 1 - 2/(1+2^(2x*log2e))
  return fmaf(-2.0f, __builtin_amdgcn_rcpf(1.0f + __builtin_amdgcn_exp2f(2.88539008f * x)), 1.0f);
}

// ---------------------------------------------------------------------------
// Weight pack kernel: gather fp32 weights into MFMA B-fragment order (bf16).
// B-fragment (16x16x32): lane holds B[k = kt*32 + (lane>>4)*8 + jj][n = lane&15]
// Sections (frag idx f, 512 bf16 each, addr = (f*64+lane)*8 + jj):
//   [0,48):   encL0  (ntile*3+kt)  A-cols: [x:0..16 | pad:16..32 | h:32..96]
//   [48,112): encL1  (ntile*4+kt)  A-cols: [h0:0..64 | h1:64..128]
//   [112,160): decL0, [160,224): decL1   (same shapes)
// ---------------------------------------------------------------------------
__global__ void pack_weights(const float* __restrict__ eWih0, const float* __restrict__ eWhh0,
                             const float* __restrict__ eWih1, const float* __restrict__ eWhh1,
                             const float* __restrict__ dWih0, const float* __restrict__ dWhh0,
                             const float* __restrict__ dWih1, const float* __restrict__ dWhh1,
                             unsigned short* __restrict__ out){
  int t = blockIdx.x * 256 + threadIdx.x;     // one thread per (frag, lane); 224*64 = 14336
  if (t >= 224 * 64) return;
  int lane = t & 63;
  int f    = t >> 6;
  const float *Wih, *Whh; int kx, ntile, kt;
  if (f < 48)       { Wih=eWih0; Whh=eWhh0; kx=16; ntile=f/3;        kt=f%3; }
  else if (f < 112) { Wih=eWih1; Whh=eWhh1; kx=64; ntile=(f-48)/4;   kt=(f-48)%4; }
  else if (f < 160) { Wih=dWih0; Whh=dWhh0; kx=16; ntile=(f-112)/3;  kt=(f-112)%3; }
  else              { Wih=dWih1; Whh=dWhh1; kx=64; ntile=(f-160)/4;  kt=(f-160)%4; }
  int n    = ntile * 16 + (lane & 15);
  int hoff = (kx == 16) ? 32 : 64;
  unsigned short vals[8];
#pragma unroll
  for (int jj = 0; jj < 8; jj++){
    int k = kt * 32 + (lane >> 4) * 8 + jj;
    float v;
    if (k < kx)        v = Wih[n * kx + k];
    else if (k < hoff) v = 0.0f;              // pad zone (layer0 only)
    else               v = Whh[n * 64 + (k - hoff)];
    vals[jj] = f2bf(v);
  }
  uint4 o;
  o.x = (unsigned)vals[0] | ((unsigned)vals[1] << 16);
  o.y = (unsigned)vals[2] | ((unsigned)vals[3] << 16);
  o.z = (unsigned)vals[4] | ((unsigned)vals[5] << 16);
  o.w = (unsigned)vals[6] | ((unsigned)vals[7] << 16);
  ((uint4*)out)[f * 64 + lane] = o;
}

// ---------------------------------------------------------------------------
// A-buffer LDS layout (fragment-packed): elem(m,k) at
//   ((k>>5)*64 + (m | (((k>>3)&3)<<4)))*8 + (k&7)   (ushort units)
// ---------------------------------------------------------------------------
__device__ __forceinline__ void write_h(unsigned short* buf, int k, int quad,
                                        const unsigned short (&h)[4]){
  unsigned short* p = buf + (((k >> 5) * 64) + quad * 4 + (((k >> 3) & 3) << 4)) * 8 + (k & 7);
#pragma unroll
  for (int e = 0; e < 4; e++) p[e * 8] = h[e];   // rows m = quad*4+e  -> lane slot +1 -> +8 elems
}

__device__ __forceinline__ void load_frags(const unsigned short* __restrict__ pw,
                                           int base0, int base1, int w, int lane,
                                           bf16x8 (&B0)[3][4], bf16x8 (&B1)[4][4]){
#pragma unroll
  for (int g = 0; g < 4; g++){
    int nt = 4 * g + w;
#pragma unroll
    for (int kt = 0; kt < 3; kt++)
      B0[kt][g] = *(const bf16x8*)(pw + (((long)(base0 + nt * 3 + kt)) * 64 + lane) * 8);
#pragma unroll
    for (int kt = 0; kt < 4; kt++)
      B1[kt][g] = *(const bf16x8*)(pw + (((long)(base1 + nt * 4 + kt)) * 64 + lane) * 8);
  }
}

template<int KT>
__device__ __forceinline__ void gemm_act(const unsigned short* __restrict__ A,
                                         const bf16x8 (&B)[KT][4],
                                         const float (&bias)[4],
                                         float (&c)[4],
                                         unsigned short (&hout)[4],
                                         int lane){
  f32x4 acc[4];
#pragma unroll
  for (int g = 0; g < 4; g++){ f32x4 a = {bias[g], bias[g], bias[g], bias[g]}; acc[g] = a; }
#pragma unroll
  for (int kt = 0; kt < KT; kt++){
    bf16x8 a = *(const bf16x8*)(A + (kt * 64 + lane) * 8);
#pragma unroll
    for (int g = 0; g < 4; g++)
      acc[g] = __builtin_amdgcn_mfma_f32_16x16x32_bf16(a, B[kt][g], acc[g], 0, 0, 0);
  }
#pragma unroll
  for (int e = 0; e < 4; e++){
    float is = sigm(acc[0][e]);
    float fs = sigm(acc[1][e]);
    float gt = tanh_(acc[2][e]);
    float os = sigm(acc[3][e]);
    c[e] = fmaf(fs, c[e], is * gt);
    hout[e] = f2bf(os * tanh_(c[e]));
  }
}

// ---------------------------------------------------------------------------
// Main kernel: one block = 16 batch rows, full encoder + decoder.
// 4 waves; wave w owns hidden slice j in [16w,16w+16) for all 4 gates.
// ---------------------------------------------------------------------------
__global__ __launch_bounds__(256, 2)
void lstm_main(const float* __restrict__ src, const float* __restrict__ trg,
               const float* __restrict__ W_in, const float* __restrict__ b_in,
               const float* __restrict__ eb0, const float* __restrict__ eb1,
               const float* __restrict__ db0, const float* __restrict__ db1,
               const float* __restrict__ Wout, const float* __restrict__ bout,
               const unsigned short* __restrict__ pw,
               float* __restrict__ out){
  __shared__ __align__(16) float sIn[16 * 256];     // src tile (16 rows x 64 t x 4)
  __shared__ __align__(16) float sTrg[16 * 256];    // trg tile
  __shared__ __align__(16) unsigned short A0[2][96 * 16];   // ping-pong, frag-packed
  __shared__ __align__(16) unsigned short A1[2][128 * 16];
  __shared__ __align__(16) float sWin[64];
  __shared__ float sBin[16];
  __shared__ __align__(16) float sWout[256];
  __shared__ float sBout[4];
  __shared__ float xfb[64];                          // decoder feedback x (16 rows x 4)

  const int tid  = threadIdx.x;
  const int lane = tid & 63;
  const int w    = tid >> 6;
  const int quad = lane >> 4;
  const int l16  = lane & 15;
  const int j    = 16 * w + l16;                     // this lane's hidden unit
  const int rowg0 = blockIdx.x * 16;

  // ---- stage src/trg tiles (coalesced float4), params, zero A buffers ----
  {
    const float4* sp4 = (const float4*)(src + (long)rowg0 * 256);
    const float4* tp4 = (const float4*)(trg + (long)rowg0 * 256);
    float4* si4 = (float4*)sIn; float4* st4 = (float4*)sTrg;
#pragma unroll
    for (int i = 0; i < 4; i++){ si4[tid + i * 256] = sp4[tid + i * 256];
                                 st4[tid + i * 256] = tp4[tid + i * 256]; }
    uint4 z; z.x = z.y = z.z = z.w = 0u;
    uint4* a0 = (uint4*)A0;                          // 2*1536 ushort = 384 uint4
    if (tid < 128) a0[tid + 256] = z;
    a0[tid] = z;
    uint4* a1 = (uint4*)A1;                          // 2*2048 ushort = 512 uint4
    a1[tid] = z; a1[tid + 256] = z;
    if (tid < 64) sWin[tid] = W_in[tid];
    if (tid < 16) sBin[tid] = b_in[tid];
    sWout[tid] = Wout[tid];
    if (tid < 4) sBout[tid] = bout[tid];
  }

  bf16x8 B0[3][4], B1[4][4];
  float bias0[4], bias1[4];
  float c0[4] = {0,0,0,0}, c1[4] = {0,0,0,0};
  load_frags(pw, 0, 48, w, lane, B0, B1);
#pragma unroll
  for (int g = 0; g < 4; g++){ int n = 64*g + 16*w + l16; bias0[g] = eb0[n]; bias1[g] = eb1[n]; }
  __syncthreads();

  unsigned short h[4];
  // ================= encoder =================
  for (int t = 0; t < 64; t++){
    int cur = t & 1, nxt = cur ^ 1;
    { // x-projection: mid = src_t @ W_in^T + b_in  -> A0[cur] x-region (k=mm)
      int r = tid >> 4, mm = tid & 15;
      float4 x  = *(const float4*)&sIn[r * 256 + t * 4];
      float4 wv = *(const float4*)&sWin[mm * 4];
      float m = sBin[mm] + x.x*wv.x + x.y*wv.y + x.z*wv.z + x.w*wv.w;
      A0[cur][(0 * 64 + (r | ((mm >> 3) << 4))) * 8 + (mm & 7)] = f2bf(m);
    }
    __syncthreads();                       // x + prev-step h visible
    gemm_act<3>(A0[cur], B0, bias0, c0, h, lane);
    write_h(A0[nxt], 32 + j, quad, h);     // h0 recurrent (next step)
    write_h(A1[cur],      j, quad, h);     // h0 -> layer1 input (this step)
    __syncthreads();                       // h0 visible for cell1
    gemm_act<4>(A1[cur], B1, bias1, c1, h, lane);
    write_h(A1[nxt], 64 + j, quad, h);     // h1 recurrent
  }

  // ================= decoder =================
  load_frags(pw, 112, 160, w, lane, B0, B1);
#pragma unroll
  for (int g = 0; g < 4; g++){ int n = 64*g + 16*w + l16; bias0[g] = db0[n]; bias1[g] = db1[n]; }
  if (tid < 64) xfb[tid] = sTrg[(tid >> 2) * 256 + (tid & 3)];   // x = trg[:,0]
  __syncthreads();                         // xfb + encoder final h visible

  for (int t = 0; t < 64; t++){
    int cur = t & 1, nxt = cur ^ 1;
    { // m = x @ W_in^T + b_in
      int r = tid >> 4, mm = tid & 15;
      float4 x  = *(const float4*)&xfb[r * 4];
      float4 wv = *(const float4*)&sWin[mm * 4];
      float m = sBin[mm] + x.x*wv.x + x.y*wv.y + x.z*wv.z + x.w*wv.w;
      A0[cur][(0 * 64 + (r | ((mm >> 3) << 4))) * 8 + (mm & 7)] = f2bf(m);
    }
    __syncthreads();                       // barA
    gemm_act<3>(A0[cur], B0, bias0, c0, h, lane);    // (h1,c1) chain
    write_h(A0[nxt], 32 + j, quad, h);
    write_h(A1[cur],      j, quad, h);
    __syncthreads();                       // barB
    gemm_act<4>(A1[cur], B1, bias1, c1, h, lane);    // (h2,c2) chain
    write_h(A1[nxt], 64 + j, quad, h);
    __syncthreads();                       // barC: h2 visible
    if (tid < 64){                         // pred = h2 @ W_out^T + b_out ; out & feedback
      int r = tid >> 2, oo = tid & 3;
      float s = sBout[oo];
      const unsigned short* Ah = A1[nxt];
#pragma unroll
      for (int jb = 0; jb < 8; jb++){
        int k0 = 64 + jb * 8;
        const unsigned short* hp = Ah + ((k0 >> 5) * 64 + (r | (((k0 >> 3) & 3) << 4))) * 8;
#pragma unroll
        for (int jj = 0; jj < 8; jj++)
          s = fmaf(bf2f(hp[jj]), sWout[oo * 64 + jb * 8 + jj], s);
      }
      float v = s + sTrg[r * 256 + t * 4 + oo];
      out[((long)(rowg0 + r)) * 256 + t * 4 + oo] = v;
      xfb[tid] = v;
    }
    __syncthreads();                       // barD: xfb visible for next m
  }
}

extern "C" void kernel_launch(void* const* d_in, const int* in_sizes, int n_in,
                              void* d_out, int out_size, void* d_ws, size_t ws_size,
                              hipStream_t stream){
  (void)n_in; (void)out_size; (void)ws_size;
  const float* src   = (const float*)d_in[0];
  const float* trg   = (const float*)d_in[1];
  const float* W_in  = (const float*)d_in[2];
  const float* b_in  = (const float*)d_in[3];
  const float* eWih0 = (const float*)d_in[4];
  const float* eWhh0 = (const float*)d_in[5];
  const float* eb0   = (const float*)d_in[6];
  const float* eWih1 = (const float*)d_in[7];
  const float* eWhh1 = (const float*)d_in[8];
  const float* eb1   = (const float*)d_in[9];
  const float* dWih0 = (const float*)d_in[10];
  const float* dWhh0 = (const float*)d_in[11];
  const float* db0   = (const float*)d_in[12];
  const float* dWih1 = (const float*)d_in[13];
  const float* dWhh1 = (const float*)d_in[14];
  const float* db1   = (const float*)d_in[15];
  const float* Wout  = (const float*)d_in[16];
  const float* bout  = (const float*)d_in[17];
  unsigned short* pw = (unsigned short*)d_ws;          // needs 229,376 bytes

  pack_weights<<<56, 256, 0, stream>>>(eWih0, eWhh0, eWih1, eWhh1,
                                       dWih0, dWhh0, dWih1, dWhh1, pw);

  int B    = in_sizes[0] / 256;                        // S*I = 256
  int nblk = B / 16;
  lstm_main<<<nblk, 256, 0, stream>>>(src, trg, W_in, b_in, eb0, eb1, db0, db1,
                                      Wout, bout, pw, (float*)d_out);
}

// Round 2
// 498.681 us; speedup vs baseline: 1.1391x; 1.1391x over previous
//
#include <hip/hip_runtime.h>

typedef __bf16 bf16x8 __attribute__((ext_vector_type(8)));
typedef float  f32x4  __attribute__((ext_vector_type(4)));

__device__ __forceinline__ unsigned short f2bf(float x){
  unsigned int u = __float_as_uint(x);
  u += 0x7fffu + ((u >> 16) & 1u);          // RNE
  return (unsigned short)(u >> 16);
}
__device__ __forceinline__ float sigm(float x){
  return __builtin_amdgcn_rcpf(1.0f + __builtin_amdgcn_exp2f(-1.44269504f * x));
}
__device__ __forceinline__ float tanh_(float x){
  return fmaf(-2.0f, __builtin_amdgcn_rcpf(1.0f + __builtin_amdgcn_exp2f(2.88539008f * x)), 1.0f);
}

// ---------------------------------------------------------------------------
// Weight pack: MFMA B-fragment order (bf16), lane holds B[k=kt*32+(lane>>4)*8+jj][n=lane&15].
// Frag sections: [0,48) encL0 (ntile*3+kt, K: x 0..16|pad|h 32..96)
//                [48,112) encL1 (ntile*4+kt, K: h0 0..64|h1 64..128)
//                [112,160) decL0, [160,224) decL1, [224,226) W_out (N=4 padded to 16, K=64)
// ---------------------------------------------------------------------------
__global__ void pack_weights(const float* __restrict__ eWih0, const float* __restrict__ eWhh0,
                             const float* __restrict__ eWih1, const float* __restrict__ eWhh1,
                             const float* __restrict__ dWih0, const float* __restrict__ dWhh0,
                             const float* __restrict__ dWih1, const float* __restrict__ dWhh1,
                             const float* __restrict__ Wout,
                             unsigned short* __restrict__ out){
  int t = blockIdx.x * 256 + threadIdx.x;
  if (t >= 226 * 64) return;
  int lane = t & 63;
  int f    = t >> 6;
  unsigned short vals[8];
  if (f >= 224){                                       // W_out frags
    int kt = f - 224, n = lane & 15;
#pragma unroll
    for (int jj = 0; jj < 8; jj++){
      int k = kt * 32 + (lane >> 4) * 8 + jj;
      vals[jj] = (n < 4) ? f2bf(Wout[n * 64 + k]) : (unsigned short)0;
    }
  } else {
    const float *Wih, *Whh; int kx, ntile, kt;
    if (f < 48)       { Wih=eWih0; Whh=eWhh0; kx=16; ntile=f/3;        kt=f%3; }
    else if (f < 112) { Wih=eWih1; Whh=eWhh1; kx=64; ntile=(f-48)/4;   kt=(f-48)%4; }
    else if (f < 160) { Wih=dWih0; Whh=dWhh0; kx=16; ntile=(f-112)/3;  kt=(f-112)%3; }
    else              { Wih=dWih1; Whh=dWhh1; kx=64; ntile=(f-160)/4;  kt=(f-160)%4; }
    int n    = ntile * 16 + (lane & 15);
    int hoff = (kx == 16) ? 32 : 64;
#pragma unroll
    for (int jj = 0; jj < 8; jj++){
      int k = kt * 32 + (lane >> 4) * 8 + jj;
      float v;
      if (k < kx)        v = Wih[n * kx + k];
      else if (k < hoff) v = 0.0f;
      else               v = Whh[n * 64 + (k - hoff)];
      vals[jj] = f2bf(v);
    }
  }
  uint4 o;
  o.x = (unsigned)vals[0] | ((unsigned)vals[1] << 16);
  o.y = (unsigned)vals[2] | ((unsigned)vals[3] << 16);
  o.z = (unsigned)vals[4] | ((unsigned)vals[5] << 16);
  o.w = (unsigned)vals[6] | ((unsigned)vals[7] << 16);
  ((uint4*)out)[f * 64 + lane] = o;
}

// A-layout (per 16-row subtile): elem(m,k) at ((k>>5)*64 + (m | (((k>>3)&3)<<4)))*8 + (k&7)
__device__ __forceinline__ void write_h(unsigned short* buf, int k, int quad,
                                        const unsigned short* h){
  unsigned short* p = buf + (((k >> 5) * 64) + quad * 4 + (((k >> 3) & 3) << 4)) * 8 + (k & 7);
#pragma unroll
  for (int e = 0; e < 4; e++) p[e * 8] = h[e];
}

__device__ __forceinline__ void load_frags(const unsigned short* __restrict__ pw,
                                           int base0, int base1, int w, int lane,
                                           bf16x8 (&B0)[3][4], bf16x8 (&B1)[4][4]){
#pragma unroll
  for (int g = 0; g < 4; g++){
    int nt = 4 * g + w;
#pragma unroll
    for (int kt = 0; kt < 3; kt++)
      B0[kt][g] = *(const bf16x8*)(pw + (((long)(base0 + nt * 3 + kt)) * 64 + lane) * 8);
#pragma unroll
    for (int kt = 0; kt < 4; kt++)
      B1[kt][g] = *(const bf16x8*)(pw + (((long)(base1 + nt * 4 + kt)) * 64 + lane) * 8);
  }
}

// One LSTM cell step for 32 rows (2 row-subtiles of 16), this wave's 16 j's.
template<int KT, int SZ>
__device__ __forceinline__ void cell_compute(const unsigned short* __restrict__ A,
                                             const bf16x8 (&B)[KT][4],
                                             const float (&bias)[4],
                                             float (&c)[8],
                                             unsigned short (&hout)[8],
                                             int lane){
  f32x4 acc[4][2];
#pragma unroll
  for (int g = 0; g < 4; g++){
    f32x4 b = {bias[g], bias[g], bias[g], bias[g]};
    acc[g][0] = b; acc[g][1] = b;
  }
#pragma unroll
  for (int kt = 0; kt < KT; kt++){
    bf16x8 a0 = *(const bf16x8*)(A +      (kt * 64 + lane) * 8);
    bf16x8 a1 = *(const bf16x8*)(A + SZ + (kt * 64 + lane) * 8);
#pragma unroll
    for (int g = 0; g < 4; g++){
      acc[g][0] = __builtin_amdgcn_mfma_f32_16x16x32_bf16(a0, B[kt][g], acc[g][0], 0, 0, 0);
      acc[g][1] = __builtin_amdgcn_mfma_f32_16x16x32_bf16(a1, B[kt][g], acc[g][1], 0, 0, 0);
    }
  }
#pragma unroll
  for (int rt = 0; rt < 2; rt++){
#pragma unroll
    for (int e = 0; e < 4; e++){
      float is = sigm(acc[0][rt][e]);
      float fs = sigm(acc[1][rt][e]);
      float gt = tanh_(acc[2][rt][e]);
      float os = sigm(acc[3][rt][e]);
      int idx = rt * 4 + e;
      c[idx] = fmaf(fs, c[idx], is * gt);
      hout[idx] = f2bf(os * tanh_(c[idx]));
    }
  }
}

// ---------------------------------------------------------------------------
// Main: one block = 32 batch rows, full encoder (1 barrier/step, layer-skewed)
// + decoder (4 barriers/step, serial feedback). 4 waves; wave w owns j-slice
// [16w,16w+16) for all 4 gates, both row-subtiles.
// ---------------------------------------------------------------------------
__global__ __launch_bounds__(256, 2)
void lstm_main(const float* __restrict__ src, const float* __restrict__ trg,
               const float* __restrict__ W_in, const float* __restrict__ b_in,
               const float* __restrict__ eb0, const float* __restrict__ eb1,
               const float* __restrict__ db0, const float* __restrict__ db1,
               const float* __restrict__ bout,
               const unsigned short* __restrict__ pw,
               float* __restrict__ out){
  __shared__ __align__(16) unsigned short A0[2][2][1536];   // ping-pong, 2 row-subtiles, K=96
  __shared__ __align__(16) unsigned short A1[2][2][2048];   // K=128
  __shared__ __align__(16) float xsrc[2][128];              // per-step x ping-pong (32 rows x 4)
  __shared__ __align__(16) float xfb[128];                  // decoder feedback x
  __shared__ __align__(16) unsigned short sWoutF[1024];     // W_out B-frags (2 x 64 x 8)

  const int tid  = threadIdx.x;
  const int lane = tid & 63;
  const int w    = tid >> 6;
  const int quad = lane >> 4;
  const int l16  = lane & 15;
  const int j    = 16 * w + l16;
  const int rowg0 = blockIdx.x * 32;
  const int mm   = tid & 15;                  // x-proj: this thread's m-unit
  const int xr   = tid >> 4;                  // x-proj: rows xr and xr+16

  // ---- staging ----
  {
    uint4 z; z.x = z.y = z.z = z.w = 0u;
    uint4* a0p = (uint4*)A0;                  // 768 uint4
    uint4* a1p = (uint4*)A1;                  // 1024 uint4
    for (int i = tid; i < 768;  i += 256) a0p[i] = z;
    for (int i = tid; i < 1024; i += 256) a1p[i] = z;
    if (tid < 128) ((uint4*)sWoutF)[tid] = ((const uint4*)pw)[224 * 64 + tid];
    if (tid < 128) xsrc[0][tid] = src[(long)(rowg0 + (tid >> 2)) * 256 + (tid & 3)];
  }
  const float4 wv = *(const float4*)&W_in[mm * 4];
  const float  bin = b_in[mm];

  bf16x8 B0[3][4], B1[4][4];
  float bias0[4], bias1[4];
  float c0[8] = {0,0,0,0,0,0,0,0}, c1[8] = {0,0,0,0,0,0,0,0};
  load_frags(pw, 0, 48, w, lane, B0, B1);
#pragma unroll
  for (int g = 0; g < 4; g++){ int n = 64*g + j; bias0[g] = eb0[n]; bias1[g] = eb1[n]; }
  __syncthreads();

  unsigned short h0r[8], h1r[8];
  const int xoff = (xr | ((mm >> 3) << 4)) * 8 + (mm & 7);   // A-layout slot for k=mm

  // ================= encoder: 1 barrier/step (cell1 skewed by 1) =================
  for (int t = 0; t < 64; t++){
    int cur = t & 1, nxt = cur ^ 1;
    float xv;
    if (tid < 128)
      xv = src[(long)(rowg0 + (tid >> 2)) * 256 + ((t == 63 ? 63 : t + 1) << 2) + (tid & 3)];
    { // x-projection for rows xr, xr+16
      float4 x0 = *(const float4*)&xsrc[cur][xr * 4];
      float4 x1 = *(const float4*)&xsrc[cur][(xr + 16) * 4];
      float m0 = bin + x0.x*wv.x + x0.y*wv.y + x0.z*wv.z + x0.w*wv.w;
      float m1 = bin + x1.x*wv.x + x1.y*wv.y + x1.z*wv.z + x1.w*wv.w;
      A0[cur][0][xoff] = f2bf(m0);
      A0[cur][1][xoff] = f2bf(m1);
    }
    if (tid < 128) xsrc[nxt][tid] = xv;
    __syncthreads();
    // cell0(t)
    cell_compute<3, 1536>(&A0[cur][0][0], B0, bias0, c0, h0r, lane);
#pragma unroll
    for (int rt = 0; rt < 2; rt++){
      write_h(&A0[nxt][rt][0], 32 + j, quad, h0r + rt * 4);   // recurrent h0
      write_h(&A1[cur][rt][0],      j, quad, h0r + rt * 4);   // feed layer 1
    }
    // cell1(t-1) — inputs written during iter t-1, visible since barrier above
    if (t > 0){
      cell_compute<4, 2048>(&A1[nxt][0][0], B1, bias1, c1, h1r, lane);
#pragma unroll
      for (int rt = 0; rt < 2; rt++)
        write_h(&A1[cur][rt][0], 64 + j, quad, h1r + rt * 4); // recurrent h1
    }
  }
  __syncthreads();
  // flush cell1(63): reads A1[1], writes recurrent into A1[0] for decoder t=0
  cell_compute<4, 2048>(&A1[1][0][0], B1, bias1, c1, h1r, lane);
#pragma unroll
  for (int rt = 0; rt < 2; rt++)
    write_h(&A1[0][rt][0], 64 + j, quad, h1r + rt * 4);

  // ================= decoder =================
  load_frags(pw, 112, 160, w, lane, B0, B1);
#pragma unroll
  for (int g = 0; g < 4; g++){ int n = 64*g + j; bias0[g] = db0[n]; bias1[g] = db1[n]; }
  const float bo = (w < 2 && l16 < 4) ? bout[l16] : 0.0f;
  if (tid < 128) xfb[tid] = trg[(long)(rowg0 + (tid >> 2)) * 256 + (tid & 3)];
  __syncthreads();

  for (int t = 0; t < 64; t++){
    int cur = t & 1, nxt = cur ^ 1;
    float tpre[4];
    if (w < 2 && l16 < 4){
#pragma unroll
      for (int e = 0; e < 4; e++)
        tpre[e] = trg[(long)(rowg0 + w * 16 + quad * 4 + e) * 256 + t * 4 + l16];
    }
    { // m = x @ W_in^T + b_in
      float4 x0 = *(const float4*)&xfb[xr * 4];
      float4 x1 = *(const float4*)&xfb[(xr + 16) * 4];
      float m0 = bin + x0.x*wv.x + x0.y*wv.y + x0.z*wv.z + x0.w*wv.w;
      float m1 = bin + x1.x*wv.x + x1.y*wv.y + x1.z*wv.z + x1.w*wv.w;
      A0[cur][0][xoff] = f2bf(m0);
      A0[cur][1][xoff] = f2bf(m1);
    }
    __syncthreads();                       // barA
    cell_compute<3, 1536>(&A0[cur][0][0], B0, bias0, c0, h0r, lane);
#pragma unroll
    for (int rt = 0; rt < 2; rt++){
      write_h(&A0[nxt][rt][0], 32 + j, quad, h0r + rt * 4);
      write_h(&A1[cur][rt][0],      j, quad, h0r + rt * 4);
    }
    __syncthreads();                       // barB
    cell_compute<4, 2048>(&A1[cur][0][0], B1, bias1, c1, h1r, lane);
#pragma unroll
    for (int rt = 0; rt < 2; rt++)
      write_h(&A1[nxt][rt][0], 64 + j, quad, h1r + rt * 4);
    __syncthreads();                       // barC: h2 visible
    if (w < 2){                            // MFMA out-projection, wave w = row-subtile w
      const unsigned short* Ah = &A1[nxt][w][0];
      bf16x8 a2 = *(const bf16x8*)(Ah + (2 * 64 + lane) * 8);
      bf16x8 a3 = *(const bf16x8*)(Ah + (3 * 64 + lane) * 8);
      bf16x8 bw0 = *(const bf16x8*)(sWoutF + lane * 8);
      bf16x8 bw1 = *(const bf16x8*)(sWoutF + 512 + lane * 8);
      f32x4 po = {bo, bo, bo, bo};
      po = __builtin_amdgcn_mfma_f32_16x16x32_bf16(a2, bw0, po, 0, 0, 0);
      po = __builtin_amdgcn_mfma_f32_16x16x32_bf16(a3, bw1, po, 0, 0, 0);
      if (l16 < 4){
#pragma unroll
        for (int e = 0; e < 4; e++){
          int row = w * 16 + quad * 4 + e;
          float v = po[e] + tpre[e];
          out[(long)(rowg0 + row) * 256 + t * 4 + l16] = v;
          xfb[row * 4 + l16] = v;
        }
      }
    }
    __syncthreads();                       // barD: xfb visible
  }
}

extern "C" void kernel_launch(void* const* d_in, const int* in_sizes, int n_in,
                              void* d_out, int out_size, void* d_ws, size_t ws_size,
                              hipStream_t stream){
  (void)n_in; (void)out_size; (void)ws_size;
  const float* src   = (const float*)d_in[0];
  const float* trg   = (const float*)d_in[1];
  const float* W_in  = (const float*)d_in[2];
  const float* b_in  = (const float*)d_in[3];
  const float* eWih0 = (const float*)d_in[4];
  const float* eWhh0 = (const float*)d_in[5];
  const float* eb0   = (const float*)d_in[6];
  const float* eWih1 = (const float*)d_in[7];
  const float* eWhh1 = (const float*)d_in[8];
  const float* eb1   = (const float*)d_in[9];
  const float* dWih0 = (const float*)d_in[10];
  const float* dWhh0 = (const float*)d_in[11];
  const float* db0   = (const float*)d_in[12];
  const float* dWih1 = (const float*)d_in[13];
  const float* dWhh1 = (const float*)d_in[14];
  const float* db1   = (const float*)d_in[15];
  const float* Wout  = (const float*)d_in[16];
  const float* bout  = (const float*)d_in[17];
  unsigned short* pw = (unsigned short*)d_ws;          // needs 231,424 bytes

  pack_weights<<<57, 256, 0, stream>>>(eWih0, eWhh0, eWih1, eWhh1,
                                       dWih0, dWhh0, dWih1, dWhh1, Wout, pw);

  int B    = in_sizes[0] / 256;                        // S*I = 256
  int nblk = B / 32;
  lstm_main<<<nblk, 256, 0, stream>>>(src, trg, W_in, b_in, eb0, eb1, db0, db1,
                                      bout, pw, (float*)d_out);
}